// Round 8
// baseline (292.980 us; speedup 1.0000x reference)
//
#include <hip/hip_runtime.h>

#define FS    5
#define NTAP  25
#define Bc    8
#define Cc    32
#define CG    8                     // channels per block
#define Hc    128
#define Wc    128
#define HW    (Hc * Wc)

#define TH      8
#define TW      64
#define HALO_H  12                   // TH + 4
#define HALO_W  72                   // [w0-4, w0+68): float4-aligned left edge
#define PLANE   (HALO_H * HALO_W)    // 864 floats
#define F4_PER_PLANE (PLANE / 4)     // 216
#define F4_TOTAL     (CG * F4_PER_PLANE)  // 1728
#define LDS_BYTES    (CG * PLANE * 4)     // 27648 B -> 4+ blocks/CU

#define STAGE_REP 12
#define GEN_REP   8
#define APPLY_REP 12

// zero-initialized device global: OOB lanes' DMA source (16B aligned)
__device__ __attribute__((aligned(16))) float ZERO4[4];

__device__ __forceinline__ void gload_lds16(const float* g, float* lds) {
    __builtin_amdgcn_global_load_lds(
        (const __attribute__((address_space(1))) void*)g,
        (__attribute__((address_space(3))) void*)lds, 16, 0, 0);
}

// shared block-id decode (identical across real + probes)
__device__ __forceinline__ void decode_bid(int bid, int& h0, int& w0,
                                           int& c0, int& b) {
    const int ht  = bid & 15;
    const int wt  = (bid >> 4) & 1;
    const int chg = (bid >> 5) & 3;
    b  = bid >> 7;
    h0 = ht * TH;
    w0 = wt * TW;
    c0 = chg * CG;
}

// DMA-stage own 8 halo planes into xs
__device__ __forceinline__ void stage_planes(const float* xo, float* xs,
                                             int h0, int w0, int tid) {
#pragma unroll
    for (int k = 0; k < 7; ++k) {
        const int f = k * 256 + tid;
        if (f < F4_TOTAL) {
            const int c  = f / F4_PER_PLANE;
            const int rm = f - c * F4_PER_PLANE;
            const int r  = rm / 18;
            const int c4 = rm - r * 18;
            const int gh = h0 - 2 + r;
            const int gw = w0 - 4 + 4 * c4;
            const bool v = ((unsigned)gh < (unsigned)Hc) &&
                           ((unsigned)gw <= (unsigned)(Wc - 4));
            const float* src = v ? (xo + (size_t)c * HW + gh * Wc + gw) : ZERO4;
            gload_lds16(src, xs + (size_t)k * 1024 + (size_t)(tid >> 6) * 256);
        }
    }
}

// ==================== REAL KERNEL (unchanged from R7) ====================
__global__ __launch_bounds__(256, 4) void ppdfn_fused(
    const float* __restrict__ x, const float* __restrict__ wg,
    const float* __restrict__ bg, float* __restrict__ out)
{
    extern __shared__ float xs[];
    const int tid = threadIdx.x;
    int h0, w0, c0, b;
    decode_bid(blockIdx.x, h0, w0, c0, b);

    const float* xb = x  + (size_t)b * Cc * HW;
    const float* xo = xb + (size_t)c0 * HW;

    stage_planes(xo, xs, h0, w0, tid);

    const int ty = tid >> 5;
    const int tx = tid & 31;
    const int w2 = tx * 2;
    const int centerOff = (h0 + ty) * Wc + (w0 + w2);

    const int chg = c0 / CG;
    const int og0 = ((chg + 1) & 3) * CG;
    const int og1 = ((chg + 2) & 3) * CG;
    const int og2 = ((chg + 3) & 3) * CG;

    float2 xoA[CG], xoB[CG];
    {
        const float* p = xb + (size_t)og0 * HW + centerOff;
#pragma unroll
        for (int u = 0; u < CG; ++u)
            xoA[u] = *reinterpret_cast<const float2*>(p + (size_t)u * HW);
    }

    float fx[NTAP], fy[NTAP];
#pragma unroll
    for (int t = 0; t < NTAP; ++t) { const float bv = bg[t]; fx[t] = bv; fy[t] = bv; }

    __syncthreads();

#pragma unroll
    for (int c = 0; c < CG; ++c) {
        const float2 xv = *reinterpret_cast<const float2*>(
            xs + c * PLANE + (ty + 2) * HALO_W + (w2 + 4));
        const float* wrow = wg + (c0 + c);
#pragma unroll
        for (int t = 0; t < NTAP; ++t) {
            const float wv = wrow[t * Cc];
            fx[t] = fmaf(wv, xv.x, fx[t]);
            fy[t] = fmaf(wv, xv.y, fy[t]);
        }
    }
    {
        const float* p = xb + (size_t)og1 * HW + centerOff;
#pragma unroll
        for (int u = 0; u < CG; ++u)
            xoB[u] = *reinterpret_cast<const float2*>(p + (size_t)u * HW);
    }
#pragma unroll
    for (int u = 0; u < CG; ++u) {
        const float2 xv = xoA[u];
        const float* wrow = wg + (og0 + u);
#pragma unroll
        for (int t = 0; t < NTAP; ++t) {
            const float wv = wrow[t * Cc];
            fx[t] = fmaf(wv, xv.x, fx[t]);
            fy[t] = fmaf(wv, xv.y, fy[t]);
        }
    }
    {
        const float* p = xb + (size_t)og2 * HW + centerOff;
#pragma unroll
        for (int u = 0; u < CG; ++u)
            xoA[u] = *reinterpret_cast<const float2*>(p + (size_t)u * HW);
    }
#pragma unroll
    for (int u = 0; u < CG; ++u) {
        const float2 xv = xoB[u];
        const float* wrow = wg + (og1 + u);
#pragma unroll
        for (int t = 0; t < NTAP; ++t) {
            const float wv = wrow[t * Cc];
            fx[t] = fmaf(wv, xv.x, fx[t]);
            fy[t] = fmaf(wv, xv.y, fy[t]);
        }
    }
#pragma unroll
    for (int u = 0; u < CG; ++u) {
        const float2 xv = xoA[u];
        const float* wrow = wg + (og2 + u);
#pragma unroll
        for (int t = 0; t < NTAP; ++t) {
            const float wv = wrow[t * Cc];
            fx[t] = fmaf(wv, xv.x, fx[t]);
            fy[t] = fmaf(wv, xv.y, fy[t]);
        }
    }

    float* ob = out + ((size_t)b * Cc + c0) * HW + centerOff;
#pragma unroll
    for (int c = 0; c < CG; ++c) {
        const float* p = xs + c * PLANE + ty * HALO_W + (w2 + 2);
        float ax = 0.f, ay = 0.f;
#pragma unroll
        for (int di = 0; di < FS; ++di) {
            const float* row = p + di * HALO_W;
            const float2 s01 = *reinterpret_cast<const float2*>(row);
            const float2 s23 = *reinterpret_cast<const float2*>(row + 2);
            const float2 s45 = *reinterpret_cast<const float2*>(row + 4);
            const float s0 = s01.x, s1 = s01.y, s2 = s23.x,
                        s3 = s23.y, s4 = s45.x, s5 = s45.y;
            ax = fmaf(fx[di * FS + 0], s0, ax);  ay = fmaf(fy[di * FS + 0], s1, ay);
            ax = fmaf(fx[di * FS + 1], s1, ax);  ay = fmaf(fy[di * FS + 1], s2, ay);
            ax = fmaf(fx[di * FS + 2], s2, ax);  ay = fmaf(fy[di * FS + 2], s3, ay);
            ax = fmaf(fx[di * FS + 3], s3, ax);  ay = fmaf(fy[di * FS + 3], s4, ay);
            ax = fmaf(fx[di * FS + 4], s4, ax);  ay = fmaf(fy[di * FS + 4], s5, ay);
        }
        *reinterpret_cast<float2*>(ob + (size_t)c * HW) = make_float2(ax, ay);
    }
}

// ==================== PROBE 1: stage x STAGE_REP ====================
__global__ __launch_bounds__(256, 4) void probe_stage(
    const float* __restrict__ x, float* __restrict__ ws)
{
    extern __shared__ float xs[];
    const int tid = threadIdx.x;
    int h0, w0, c0, b;
    decode_bid(blockIdx.x, h0, w0, c0, b);
    const float* xo = x + ((size_t)b * Cc + c0) * HW;

#pragma unroll 1
    for (int rep = 0; rep < STAGE_REP; ++rep) {
        stage_planes(xo, xs, h0, w0, tid);
        asm volatile("s_waitcnt vmcnt(0)" ::: "memory");
        __syncthreads();
    }
    ws[(size_t)blockIdx.x * 256 + tid] = xs[tid];
}

// ==================== PROBE 2: gen x GEN_REP ====================
__global__ __launch_bounds__(256, 4) void probe_gen(
    const float* __restrict__ x, const float* __restrict__ wg,
    const float* __restrict__ bg, float* __restrict__ ws)
{
    extern __shared__ float xs[];
    const int tid = threadIdx.x;
    int h0, w0, c0, b;
    decode_bid(blockIdx.x, h0, w0, c0, b);
    const float* xb = x  + (size_t)b * Cc * HW;
    const float* xo = xb + (size_t)c0 * HW;

    stage_planes(xo, xs, h0, w0, tid);
    asm volatile("s_waitcnt vmcnt(0)" ::: "memory");
    __syncthreads();

    const int ty = tid >> 5;
    const int tx = tid & 31;
    const int chg = c0 / CG;
    const int og0 = ((chg + 1) & 3) * CG;
    const int og1 = ((chg + 2) & 3) * CG;
    const int og2 = ((chg + 3) & 3) * CG;

    // taps accumulate ACROSS reps -> every FMA chain stays live
    float fx[NTAP], fy[NTAP];
#pragma unroll
    for (int t = 0; t < NTAP; ++t) { const float bv = bg[t]; fx[t] = bv; fy[t] = bv; }

#pragma unroll 1
    for (int rep = 0; rep < GEN_REP; ++rep) {
        const int wc = (tx * 2 + 2 * rep) & 63;             // shifted column, in-tile
        const int co = (h0 + ty) * Wc + (w0 + wc);
        // own 8 from LDS
#pragma unroll
        for (int c = 0; c < CG; ++c) {
            const float2 xv = *reinterpret_cast<const float2*>(
                xs + c * PLANE + (ty + 2) * HALO_W + (wc + 4));
            const float* wrow = wg + (c0 + c);
#pragma unroll
            for (int t = 0; t < NTAP; ++t) {
                const float wv = wrow[t * Cc];
                fx[t] = fmaf(wv, xv.x, fx[t]);
                fy[t] = fmaf(wv, xv.y, fy[t]);
            }
        }
        // other 24 from global, ping-pong
        float2 xoA[CG], xoB[CG];
        {
            const float* p = xb + (size_t)og0 * HW + co;
#pragma unroll
            for (int u = 0; u < CG; ++u)
                xoA[u] = *reinterpret_cast<const float2*>(p + (size_t)u * HW);
        }
        {
            const float* p = xb + (size_t)og1 * HW + co;
#pragma unroll
            for (int u = 0; u < CG; ++u)
                xoB[u] = *reinterpret_cast<const float2*>(p + (size_t)u * HW);
        }
#pragma unroll
        for (int u = 0; u < CG; ++u) {
            const float2 xv = xoA[u];
            const float* wrow = wg + (og0 + u);
#pragma unroll
            for (int t = 0; t < NTAP; ++t) {
                const float wv = wrow[t * Cc];
                fx[t] = fmaf(wv, xv.x, fx[t]);
                fy[t] = fmaf(wv, xv.y, fy[t]);
            }
        }
        {
            const float* p = xb + (size_t)og2 * HW + co;
#pragma unroll
            for (int u = 0; u < CG; ++u)
                xoA[u] = *reinterpret_cast<const float2*>(p + (size_t)u * HW);
        }
#pragma unroll
        for (int u = 0; u < CG; ++u) {
            const float2 xv = xoB[u];
            const float* wrow = wg + (og1 + u);
#pragma unroll
            for (int t = 0; t < NTAP; ++t) {
                const float wv = wrow[t * Cc];
                fx[t] = fmaf(wv, xv.x, fx[t]);
                fy[t] = fmaf(wv, xv.y, fy[t]);
            }
        }
#pragma unroll
        for (int u = 0; u < CG; ++u) {
            const float2 xv = xoA[u];
            const float* wrow = wg + (og2 + u);
#pragma unroll
            for (int t = 0; t < NTAP; ++t) {
                const float wv = wrow[t * Cc];
                fx[t] = fmaf(wv, xv.x, fx[t]);
                fy[t] = fmaf(wv, xv.y, fy[t]);
            }
        }
    }
    float s = 0.f;
#pragma unroll
    for (int t = 0; t < NTAP; ++t) s += fx[t] + fy[t];
    ws[(size_t)262144 + (size_t)blockIdx.x * 256 + tid] = s;
}

// ==================== PROBE 3: apply x APPLY_REP ====================
__global__ __launch_bounds__(256, 4) void probe_apply(
    const float* __restrict__ x, const float* __restrict__ bg,
    float* __restrict__ ws)
{
    extern __shared__ float xs[];
    const int tid = threadIdx.x;
    int h0, w0, c0, b;
    decode_bid(blockIdx.x, h0, w0, c0, b);
    const float* xo = x + ((size_t)b * Cc + c0) * HW;

    stage_planes(xo, xs, h0, w0, tid);
    asm volatile("s_waitcnt vmcnt(0)" ::: "memory");
    __syncthreads();

    const int ty = tid >> 5;
    const int tx = tid & 31;
    const int w2 = tx * 2;

    float f[NTAP];
#pragma unroll
    for (int t = 0; t < NTAP; ++t) f[t] = bg[t];   // runtime values (constant filters)

    float ax = 0.f, ay = 0.f;                      // chained across reps -> live
#pragma unroll 1
    for (int rep = 0; rep < APPLY_REP; ++rep) {
#pragma unroll
        for (int c = 0; c < CG; ++c) {
            const int cc = (c + rep) & (CG - 1);   // rep-dependent plane -> no hoist
            const float* p = xs + cc * PLANE + ty * HALO_W + (w2 + 2);
#pragma unroll
            for (int di = 0; di < FS; ++di) {
                const float* row = p + di * HALO_W;
                const float2 s01 = *reinterpret_cast<const float2*>(row);
                const float2 s23 = *reinterpret_cast<const float2*>(row + 2);
                const float2 s45 = *reinterpret_cast<const float2*>(row + 4);
                const float s0 = s01.x, s1 = s01.y, s2 = s23.x,
                            s3 = s23.y, s4 = s45.x, s5 = s45.y;
                ax = fmaf(f[di * FS + 0], s0, ax);  ay = fmaf(f[di * FS + 0], s1, ay);
                ax = fmaf(f[di * FS + 1], s1, ax);  ay = fmaf(f[di * FS + 1], s2, ay);
                ax = fmaf(f[di * FS + 2], s2, ax);  ay = fmaf(f[di * FS + 2], s3, ay);
                ax = fmaf(f[di * FS + 3], s3, ax);  ay = fmaf(f[di * FS + 3], s4, ay);
                ax = fmaf(f[di * FS + 4], s4, ax);  ay = fmaf(f[di * FS + 4], s5, ay);
            }
        }
    }
    ws[(size_t)524288 + (size_t)blockIdx.x * 256 + tid] = ax + ay;
}

extern "C" void kernel_launch(void* const* d_in, const int* in_sizes, int n_in,
                              void* d_out, int out_size, void* d_ws, size_t ws_size,
                              hipStream_t stream) {
    const float* x  = (const float*)d_in[0];
    const float* wg = (const float*)d_in[1];
    const float* bg = (const float*)d_in[2];
    float* out = (float*)d_out;
    float* ws  = (float*)d_ws;

    // real kernel first: d_out must be correct
    ppdfn_fused<<<dim3(1024), 256, LDS_BYTES, stream>>>(x, wg, bg, out);
    // measurement probes (write only to d_ws)
    probe_stage<<<dim3(1024), 256, LDS_BYTES, stream>>>(x, ws);
    probe_gen  <<<dim3(1024), 256, LDS_BYTES, stream>>>(x, wg, bg, ws);
    probe_apply<<<dim3(1024), 256, LDS_BYTES, stream>>>(x, bg, ws);
}

// Round 9
// 29.418 us; speedup vs baseline: 9.9591x; 9.9591x over previous
//
#include <hip/hip_runtime.h>

#define FS    5
#define NTAP  25
#define Cc    32
#define Hc    128
#define Wc    128
#define HW    (Hc * Wc)

#define TH      8
#define TW      64
#define HALO_H  12                    // TH + 4
#define HALO_W  72                    // [w0-4, w0+68): float4-aligned
#define PLANE   (HALO_H * HALO_W)     // 864 floats
#define F4_PER_PLANE (PLANE / 4)      // 216
#define F4_TOTAL     (Cc * F4_PER_PLANE)   // 6912
#define DMA_PER_THREAD (F4_TOTAL / 256)    // 27
#define LDS_BYTES (Cc * PLANE * 4)    // 110592 B -> 1 block/CU

// zero-initialized device global: OOB lanes' DMA source (16B aligned)
__device__ __attribute__((aligned(16))) float ZERO4[4];

__device__ __forceinline__ void gload_lds16(const float* g, float* lds) {
    __builtin_amdgcn_global_load_lds(
        (const __attribute__((address_space(1))) void*)g,
        (__attribute__((address_space(3))) void*)lds, 16, 0, 0);
}

// One block = one 8x64 tile of one image, ALL 32 channels (no gen redundancy).
// DMA-stage all 27 dwordx4/thread; vmcnt(13) barrier -> ch 0..15 ready;
// genA (pure s_load-weight FMA stream, centers pre-read to VGPRs);
// vmcnt(0) barrier -> genB; apply 5x5 from LDS (2 px/thread, float2).
__global__ __launch_bounds__(256) void ppdfn_fused(
    const float* __restrict__ x, const float* __restrict__ wg,
    const float* __restrict__ bg, float* __restrict__ out)
{
    extern __shared__ float xs[];     // [Cc][HALO_H][HALO_W]

    const int tid = threadIdx.x;
    const int ht  = blockIdx.x;       // 0..15
    const int wt  = blockIdx.y;       // 0..1
    const int b   = blockIdx.z;       // 0..7
    const int h0  = ht * TH;
    const int w0  = wt * TW;

    const float* xb = x + (size_t)b * Cc * HW;

    // ---- phase 1: issue ALL 27 DMA dwordx4 per thread ----
    // flat f4 index f = k*256 + tid -> (c, r, c4); LDS filled linearly.
#pragma unroll
    for (int k = 0; k < DMA_PER_THREAD; ++k) {
        const int f  = k * 256 + tid;
        const int c  = f / F4_PER_PLANE;          // /216 (magic mul)
        const int rm = f - c * F4_PER_PLANE;
        const int r  = rm / 18;
        const int c4 = rm - r * 18;
        const int gh = h0 - 2 + r;
        const int gw = w0 - 4 + 4 * c4;
        const bool v = ((unsigned)gh < (unsigned)Hc) &&
                       ((unsigned)gw <= (unsigned)(Wc - 4));
        const float* src = v ? (xb + (size_t)c * HW + gh * Wc + gw) : ZERO4;
        gload_lds16(src, xs + (size_t)k * 1024 + (size_t)(tid >> 6) * 256);
    }

    const int ty = tid >> 5;          // 0..7
    const int tx = tid & 31;          // 0..31
    const int w2 = tx * 2;

    float fx[NTAP], fy[NTAP];
#pragma unroll
    for (int t = 0; t < NTAP; ++t) { const float bv = bg[t]; fx[t] = bv; fy[t] = bv; }

    // wait until first 14 DMA instrs done (covers channels 0..15), all waves
    asm volatile("s_waitcnt vmcnt(13)" ::: "memory");
    __builtin_amdgcn_sched_barrier(0);
    __builtin_amdgcn_s_barrier();

    // ---- genA: channels 0..15 (centers to VGPRs first, then pure FMA) ----
    float2 cv[16];
#pragma unroll
    for (int c = 0; c < 16; ++c)
        cv[c] = *reinterpret_cast<const float2*>(
            xs + c * PLANE + (ty + 2) * HALO_W + (w2 + 4));
#pragma unroll
    for (int t = 0; t < NTAP; ++t) {
        const float* wr = wg + t * Cc;            // wg[t][0..15]: consecutive
#pragma unroll
        for (int c = 0; c < 16; ++c) {
            const float wv = wr[c];               // uniform -> s_load chunks
            fx[t] = fmaf(wv, cv[c].x, fx[t]);
            fy[t] = fmaf(wv, cv[c].y, fy[t]);
        }
    }

    // all DMA complete -> channels 16..31 ready
    asm volatile("s_waitcnt vmcnt(0)" ::: "memory");
    __builtin_amdgcn_sched_barrier(0);
    __builtin_amdgcn_s_barrier();

    // ---- genB: channels 16..31 ----
#pragma unroll
    for (int c = 0; c < 16; ++c)
        cv[c] = *reinterpret_cast<const float2*>(
            xs + (c + 16) * PLANE + (ty + 2) * HALO_W + (w2 + 4));
#pragma unroll
    for (int t = 0; t < NTAP; ++t) {
        const float* wr = wg + t * Cc + 16;       // wg[t][16..31]
#pragma unroll
        for (int c = 0; c < 16; ++c) {
            const float wv = wr[c];
            fx[t] = fmaf(wv, cv[c].x, fx[t]);
            fy[t] = fmaf(wv, cv[c].y, fy[t]);
        }
    }

    // ---- apply: 5x5 over all 32 channels, 2 px/thread ----
    float* ob = out + (size_t)b * Cc * HW + (h0 + ty) * Wc + (w0 + w2);
#pragma unroll 2
    for (int c = 0; c < Cc; ++c) {
        const float* p = xs + c * PLANE + ty * HALO_W + (w2 + 2);
        float ax = 0.f, ay = 0.f;
#pragma unroll
        for (int di = 0; di < FS; ++di) {
            const float* row = p + di * HALO_W;
            const float2 s01 = *reinterpret_cast<const float2*>(row);
            const float2 s23 = *reinterpret_cast<const float2*>(row + 2);
            const float2 s45 = *reinterpret_cast<const float2*>(row + 4);
            const float s0 = s01.x, s1 = s01.y, s2 = s23.x,
                        s3 = s23.y, s4 = s45.x, s5 = s45.y;
            ax = fmaf(fx[di * FS + 0], s0, ax);  ay = fmaf(fy[di * FS + 0], s1, ay);
            ax = fmaf(fx[di * FS + 1], s1, ax);  ay = fmaf(fy[di * FS + 1], s2, ay);
            ax = fmaf(fx[di * FS + 2], s2, ax);  ay = fmaf(fy[di * FS + 2], s3, ay);
            ax = fmaf(fx[di * FS + 3], s3, ax);  ay = fmaf(fy[di * FS + 3], s4, ay);
            ax = fmaf(fx[di * FS + 4], s4, ax);  ay = fmaf(fy[di * FS + 4], s5, ay);
        }
        *reinterpret_cast<float2*>(ob + (size_t)c * HW) = make_float2(ax, ay);
    }
}

extern "C" void kernel_launch(void* const* d_in, const int* in_sizes, int n_in,
                              void* d_out, int out_size, void* d_ws, size_t ws_size,
                              hipStream_t stream) {
    const float* x  = (const float*)d_in[0];
    const float* wg = (const float*)d_in[1];
    const float* bg = (const float*)d_in[2];
    float* out = (float*)d_out;

    ppdfn_fused<<<dim3(Hc / TH, Wc / TW, 8), 256, LDS_BYTES, stream>>>(
        x, wg, bg, out);
}

// Round 10
// 26.498 us; speedup vs baseline: 11.0566x; 1.1102x over previous
//
#include <hip/hip_runtime.h>

#define FS    5
#define NTAP  25
#define Cc    32
#define CG    8                     // channels per block
#define Hc    128
#define Wc    128
#define HW    (Hc * Wc)

#define TH      8
#define TW      64
#define HALO_H  12                   // TH + 4
#define HALO_W  72                   // [w0-4, w0+68): float4-aligned left edge
#define PLANE   (HALO_H * HALO_W)    // 864 floats
#define F4_PER_PLANE (PLANE / 4)     // 216
#define F4_TOTAL     (CG * F4_PER_PLANE)  // 1728
#define LDS_BYTES    (CG * PLANE * 4)     // 27648 B

// zero-initialized device global: OOB lanes' DMA source (16B aligned)
__device__ __attribute__((aligned(16))) float ZERO4[4];

__device__ __forceinline__ void gload_lds16(const float* g, float* lds) {
    __builtin_amdgcn_global_load_lds(
        (const __attribute__((address_space(1))) void*)g,
        (__attribute__((address_space(3))) void*)lds, 16, 0, 0);
}

// One block = one 8x64 tile of one image, ONE 8-channel group (apply side).
// Stage own 8 halo planes via global_load_lds DMA (27.6 KB LDS, 3 blocks/CU).
// Gen (all 32 ch, 4x redundant across sibling blocks): centers in cv[32]
// via channel ROTATION [own8,+8,+16,+24] (static reg indices); 24 non-own
// centers = coalesced global float2 loads issued before the barrier; FMA
// stream is t-outer so each (t,group) reads 8 CONSECUTIVE weights
// (s_load_dwordx8) instead of 8 stride-128B scalar loads.
// Apply: 5x5 over own 8 ch from LDS, 2 px/thread (float2). One barrier.
__global__ __launch_bounds__(256, 3) void ppdfn_fused(
    const float* __restrict__ x, const float* __restrict__ wg,
    const float* __restrict__ bg, float* __restrict__ out)
{
    extern __shared__ float xs[];     // [CG][HALO_H][HALO_W]

    const int tid = threadIdx.x;
    const int bid = blockIdx.x;
    // id = ht + 16*wt + 32*chg + 128*b ; delta(chg)=32 == 0 mod 8 -> the 4
    // ch-group blocks of one tile land on the same XCD (L2 locality for
    // the gen center reads).
    const int ht  = bid & 15;
    const int wt  = (bid >> 4) & 1;
    const int chg = (bid >> 5) & 3;
    const int b   = bid >> 7;
    const int h0  = ht * TH;
    const int w0  = wt * TW;
    const int c0  = chg * CG;

    const float* xb = x  + (size_t)b * Cc * HW;
    const float* xo = xb + (size_t)c0 * HW;

    // ---- phase 1: DMA-stage own 8 halo planes (<=7 dwordx4 per thread) ----
#pragma unroll
    for (int k = 0; k < 7; ++k) {
        const int f = k * 256 + tid;
        if (f < F4_TOTAL) {                      // k==6: wave-uniform guard
            const int c  = f / F4_PER_PLANE;     // /216 (magic mul)
            const int rm = f - c * F4_PER_PLANE;
            const int r  = rm / 18;
            const int c4 = rm - r * 18;
            const int gh = h0 - 2 + r;
            const int gw = w0 - 4 + 4 * c4;
            const bool v = ((unsigned)gh < (unsigned)Hc) &&
                           ((unsigned)gw <= (unsigned)(Wc - 4));
            const float* src = v ? (xo + (size_t)c * HW + gh * Wc + gw) : ZERO4;
            gload_lds16(src, xs + (size_t)k * 1024 + (size_t)(tid >> 6) * 256);
        }
    }

    // ---- per-pixel coords (2 px per thread) ----
    const int ty = tid >> 5;          // 0..7
    const int tx = tid & 31;          // 0..31
    const int w2 = tx * 2;
    const int centerOff = (h0 + ty) * Wc + (w0 + w2);

    // rotation group base channels (uniform, runtime)
    const int g1 = (c0 + 8)  & 31;
    const int g2 = (c0 + 16) & 31;
    const int g3 = (c0 + 24) & 31;

    // ---- issue 24 non-own center loads (coalesced float2) before barrier ----
    float2 cv[32];                    // all indices STATIC (rule #20)
    {
        const float* cb = xb + centerOff;
#pragma unroll
        for (int u = 0; u < 8; ++u)
            cv[8 + u] = *reinterpret_cast<const float2*>(cb + (size_t)(g1 + u) * HW);
#pragma unroll
        for (int u = 0; u < 8; ++u)
            cv[16 + u] = *reinterpret_cast<const float2*>(cb + (size_t)(g2 + u) * HW);
#pragma unroll
        for (int u = 0; u < 8; ++u)
            cv[24 + u] = *reinterpret_cast<const float2*>(cb + (size_t)(g3 + u) * HW);
    }

    float fx[NTAP], fy[NTAP];
#pragma unroll
    for (int t = 0; t < NTAP; ++t) { const float bv = bg[t]; fx[t] = bv; fy[t] = bv; }

    // DMA complete (and center loads drained) -> own planes readable
    asm volatile("s_waitcnt vmcnt(0)" ::: "memory");
    __builtin_amdgcn_sched_barrier(0);
    __builtin_amdgcn_s_barrier();

    // own 8 center values from LDS (slots 0..7 of the rotation)
#pragma unroll
    for (int u = 0; u < 8; ++u)
        cv[u] = *reinterpret_cast<const float2*>(
            xs + u * PLANE + (ty + 2) * HALO_W + (w2 + 4));

    // ---- gen: t-outer FMA stream; weights per (t,group) are 8 consecutive ----
#pragma unroll
    for (int t = 0; t < NTAP; ++t) {
        const float* wr = wg + t * Cc;
#pragma unroll
        for (int u = 0; u < 8; ++u) {             // own group: wg[t][c0..c0+7]
            const float wv = wr[c0 + u];
            fx[t] = fmaf(wv, cv[u].x, fx[t]);
            fy[t] = fmaf(wv, cv[u].y, fy[t]);
        }
#pragma unroll
        for (int u = 0; u < 8; ++u) {             // wg[t][g1..g1+7]
            const float wv = wr[g1 + u];
            fx[t] = fmaf(wv, cv[8 + u].x, fx[t]);
            fy[t] = fmaf(wv, cv[8 + u].y, fy[t]);
        }
#pragma unroll
        for (int u = 0; u < 8; ++u) {             // wg[t][g2..g2+7]
            const float wv = wr[g2 + u];
            fx[t] = fmaf(wv, cv[16 + u].x, fx[t]);
            fy[t] = fmaf(wv, cv[16 + u].y, fy[t]);
        }
#pragma unroll
        for (int u = 0; u < 8; ++u) {             // wg[t][g3..g3+7]
            const float wv = wr[g3 + u];
            fx[t] = fmaf(wv, cv[24 + u].x, fx[t]);
            fy[t] = fmaf(wv, cv[24 + u].y, fy[t]);
        }
    }

    // ---- apply: 5x5 over own 8 channels (unchanged from R7) ----
    float* ob = out + ((size_t)b * Cc + c0) * HW + centerOff;
#pragma unroll
    for (int c = 0; c < CG; ++c) {
        const float* p = xs + c * PLANE + ty * HALO_W + (w2 + 2);
        float ax = 0.f, ay = 0.f;
#pragma unroll
        for (int di = 0; di < FS; ++di) {
            const float* row = p + di * HALO_W;
            const float2 s01 = *reinterpret_cast<const float2*>(row);
            const float2 s23 = *reinterpret_cast<const float2*>(row + 2);
            const float2 s45 = *reinterpret_cast<const float2*>(row + 4);
            const float s0 = s01.x, s1 = s01.y, s2 = s23.x,
                        s3 = s23.y, s4 = s45.x, s5 = s45.y;
            ax = fmaf(fx[di * FS + 0], s0, ax);  ay = fmaf(fy[di * FS + 0], s1, ay);
            ax = fmaf(fx[di * FS + 1], s1, ax);  ay = fmaf(fy[di * FS + 1], s2, ay);
            ax = fmaf(fx[di * FS + 2], s2, ax);  ay = fmaf(fy[di * FS + 2], s3, ay);
            ax = fmaf(fx[di * FS + 3], s3, ax);  ay = fmaf(fy[di * FS + 3], s4, ay);
            ax = fmaf(fx[di * FS + 4], s4, ax);  ay = fmaf(fy[di * FS + 4], s5, ay);
        }
        *reinterpret_cast<float2*>(ob + (size_t)c * HW) = make_float2(ax, ay);
    }
}

extern "C" void kernel_launch(void* const* d_in, const int* in_sizes, int n_in,
                              void* d_out, int out_size, void* d_ws, size_t ws_size,
                              hipStream_t stream) {
    const float* x  = (const float*)d_in[0];
    const float* wg = (const float*)d_in[1];
    const float* bg = (const float*)d_in[2];
    float* out = (float*)d_out;

    ppdfn_fused<<<dim3(1024), 256, LDS_BYTES, stream>>>(x, wg, bg, out);
}